// Round 8
// baseline (148.450 us; speedup 1.0000x reference)
//
#include <hip/hip_runtime.h>
#include <hip/hip_bf16.h>

#define B_  16
#define E_  8192
#define NN_ 384
#define N1_ 385
#define H_  32
#define HH_ 16                      // h-planes per block (half of H)
#define PLANE_ (N1_ * N1_)          // 148225
#define TOTAL_ (B_ * H_ * PLANE_)   // 75,891,200
#define CAP_ 128                    // bin capacity (avg fill ~38)
#define NBIN_ (B_ * N1_)            // 6160 bins keyed by (b, row_index_1based)
#define STRIDE_ 396                 // LDS row stride: %4==0 (float4-able)
#define TS_ 21                      // table stride: gcd(21,32)=1 -> full bank spread
#define GBLK_ 1024                  // persistent grid: 4 blocks/CU * 256 CU
#define RSTRIDE_ (GBLK_ / 2)        // 512 row-stride per half

typedef float vfloat4 __attribute__((ext_vector_type(4)));   // native vec for nontemporal

// workspace layout (bytes)
#define WS_COUNTS 0                           // 6160*4 = 24640
#define WS_T      32768                       // 32*4
#define WS_A      33024                       // 33*32*4 = 4224
#define WS_B      (33024 + 33*32*4)           // ends 41472 < 65536
#define WS_BINS2  65536                       // 6160*128*8 = 6,307,840
#define WS_NEED   ((size_t)WS_BINS2 + (size_t)NBIN_*CAP_*8)   // 6,373,376

// ============================================================================
// FAST PATH
// ============================================================================

// Fused: zero counts (all blocks) + piecewise-linear MLP precompute (block 0).
// f_h(d) = b2_h + sum_k relu(d*W1_k+b1_k)*W2[h][k] is piecewise-linear with
// breakpoints t_k = -b1_k/W1_k; per sorted segment s: f_h(d) = A[s][h]+d*Bv[s][h].
__global__ __launch_bounds__(256) void prep_kernel(
    const float* __restrict__ W1, const float* __restrict__ b1,
    const float* __restrict__ W2, const float* __restrict__ b2,
    float* __restrict__ T, float* __restrict__ A, float* __restrict__ Bv,
    int* __restrict__ counts)
{
    int g = blockIdx.x * 256 + threadIdx.x;
    if (g < NBIN_) counts[g] = 0;

    if (blockIdx.x == 0) {
        __shared__ float sTv[32], sT[32], sW1[32], sb1[32];
        int tid = threadIdx.x;
        if (tid < 32) {
            float w = W1[tid], b = b1[tid];
            sW1[tid] = w; sb1[tid] = b;
            sTv[tid] = (w != 0.0f) ? (-b / w) : -3.402823e38f;
        }
        __syncthreads();
        if (tid < 32) {                 // stable rank sort
            float t = sTv[tid];
            int rank = 0;
            for (int j = 0; j < 32; ++j) {
                float tj = sTv[j];
                rank += (tj < t || (tj == t && j < tid)) ? 1 : 0;
            }
            sT[rank] = t;
        }
        __syncthreads();
        if (tid < 32) T[tid] = sT[tid];
        for (int idx = tid; idx < 33 * 32; idx += 256) {
            int s = idx >> 5, h = idx & 31;
            float m;
            if (s == 0)       m = sT[0] - 1.0f;
            else if (s == 32) m = sT[31] + 1.0f;
            else              m = 0.5f * (sT[s - 1] + sT[s]);
            float alpha = b2[h], beta = 0.0f;
            for (int k = 0; k < 32; ++k) {
                float w = sW1[k], b = sb1[k];
                bool act = (w > 0.0f) ? (m > -b / w)
                         : (w < 0.0f) ? (m < -b / w) : (b > 0.0f);
                if (act) {
                    float w2 = W2[h * 32 + k];
                    alpha = fmaf(w2, b, alpha);
                    beta  = fmaf(w2, w, beta);
                }
            }
            A[idx] = alpha; Bv[idx] = beta;
        }
    }
}

// Per valid edge: push entry into both endpoint bins.
// meta = (lo<<16) | (r<<9) | other;  lo = dist's PL segment, r = type row,
// other = opposite endpoint (1-based). dist stored alongside.
__global__ __launch_bounds__(256) void bin_kernel(
    const float4* __restrict__ edge_feat,   // (B,E,4)
    const int*    __restrict__ edge_index,  // (B,2,E)
    const void*   __restrict__ edge_mask,   // (B,E) bool(1B) or int32 — detected
    const int*    __restrict__ nlig,        // (B,)
    const float*  __restrict__ T,           // (32) sorted breakpoints
    int* __restrict__ counts, int2* __restrict__ bins2)
{
    int lane = threadIdx.x & 63;
    int probe = ((const int*)edge_mask)[lane];
    bool byte_mask = __any(probe != 0 && probe != 1);

    int gid = blockIdx.x * blockDim.x + threadIdx.x;   // exact grid: B*E
    int b = gid >> 13, e = gid & (E_ - 1);
    bool m = byte_mask ? (((const unsigned char*)edge_mask)[gid] != 0)
                       : (((const int*)edge_mask)[gid] != 0);
    if (!m) return;
    int src = edge_index[(b * 2 + 0) * E_ + e];
    int tgt = edge_index[(b * 2 + 1) * E_ + e];
    if (src < 0 || src >= NN_ || tgt < 0 || tgt >= NN_) return;
    if (src == 0 && tgt == 0) return;

    float4 ef = edge_feat[gid];
    int c0 = (int)ef.x, c1 = (int)ef.y, c2 = (int)ef.z;
    float dist = ef.w;

    int r;
    if (c0 == 0 || c0 == 1) {
        r = min(max(c0 * 4 + c1 * 2 + c2, 0), 19);
    } else if (c0 == 5) {
        int pi = min(max(c1, 0), 14);
        int nl = nlig[b];
        bool sl = src < nl, tl = tgt < nl;
        int loc = (sl && tl) ? 0 : ((!sl && !tl) ? 1 : 2);
        r = 20 + loc * 15 + pi;
    } else r = 65;   // zero row

    // segment index: #{T[k] < dist}
    int lo = 0;
#pragma unroll
    for (int q = 0; q < 8; ++q) {
        float4 tv = *reinterpret_cast<const float4*>(T + 4 * q);
        lo += (tv.x < dist) ? 1 : 0;
        lo += (tv.y < dist) ? 1 : 0;
        lo += (tv.z < dist) ? 1 : 0;
        lo += (tv.w < dist) ? 1 : 0;
    }

    int s1 = src + 1, t1 = tgt + 1;
    int db = __float_as_int(dist);
    int base = (lo << 16) | (r << 9);
    int bin1 = b * N1_ + s1, bin2i = b * N1_ + t1;
    int p = atomicAdd(&counts[bin1], 1);
    if (p < CAP_) bins2[bin1 * CAP_ + p] = make_int2(base | t1, db);
    p = atomicAdd(&counts[bin2i], 1);
    if (p < CAP_) bins2[bin2i * CAP_ + p] = make_int2(base | s1, db);
}

// Persistent grid: 1024 blocks (4/CU); block handles one h-half and rows
// rowid = (bid>>1) + 512*k (grid-stride) -> ~12 rows each, no dispatch tail.
// 512 threads = 8 waves; each WAVE owns 2 h-planes (wave-private LDS strip)
// -> no barriers in the row loop. Next row's count + first 2 entry batches
// are prefetched into registers during the current row (latency pipeline).
// LDS rows are SHIFTED: column t lives at (4-off)+t, off=(4-((h+i)&3))&3, so
// LDS float4 and global dwordx4 accesses are both 16B-aligned.
__global__ __launch_bounds__(512, 8) void chunk_kernel(
    const float* __restrict__ structural_w,   // (20,H)
    const float* __restrict__ plip_protein_w, // (15,H)
    const float* __restrict__ plip_ligand_w,  // (15,H)
    const float* __restrict__ plip_inter_w,   // (15,H)
    const float* __restrict__ loc_w,          // (4,H)
    const float* __restrict__ virtual_w,      // (1,H)
    const float* __restrict__ A,              // (33,32)
    const float* __restrict__ Bv,             // (33,32)
    const int*   __restrict__ counts,         // (NBIN_)
    const int2*  __restrict__ bins2,          // (NBIN_,CAP_)
    float* __restrict__ out)                  // (B,H,N1,N1)
{
    __shared__ float4 srow4[HH_ * (STRIDE_ / 4)];   // 25344 B; wave w owns rows 2w,2w+1
    __shared__ float sA[33 * TS_], sB[33 * TS_];    // 2772 B each
    __shared__ float sType[66 * TS_];               // 5544 B
    float* srow = reinterpret_cast<float*>(srow4);

    int bid = blockIdx.x;
    int half = bid & 1;
    int rbase = bid >> 1;            // 0..511
    int h0 = half << 4;
    int tid = threadIdx.x;
    int wv = tid >> 6, lane = tid & 63;

    // ---- stage tables (once per block) ----
    for (int idx = tid; idx < 33 * 16; idx += 512) {
        int s = idx >> 4, hh = idx & 15;
        sA[s * TS_ + hh] = A[s * 32 + h0 + hh];
        sB[s * TS_ + hh] = Bv[s * 32 + h0 + hh];
    }
    for (int idx = tid; idx < 66 * 16; idx += 512) {
        int r = idx >> 4, hh = idx & 15;
        float v;
        if (r < 20) v = structural_w[r * 32 + h0 + hh];
        else if (r < 65) {
            int t2 = r - 20;
            int loc = t2 / 15, pi = t2 - loc * 15;
            const float* pw = (loc == 0) ? plip_ligand_w
                            : (loc == 1) ? plip_protein_w : plip_inter_w;
            v = pw[pi * 32 + h0 + hh] + loc_w[loc * 32 + h0 + hh];
        } else v = 0.0f;
        sType[r * TS_ + hh] = v;
    }

    int hh_q = lane & 1;             // plane within wave's pair
    int slot = lane >> 1;            // entry slot 0..31
    int hhg  = (wv << 1) | hh_q;     // hh within half, 0..15
    int hq   = h0 + hhg;             // global h for gather lane
    float* sW = srow + (wv << 1) * STRIDE_;   // wave-private strip (2 rows)

    int rw = lane >> 5;              // writeout: plane 0..1 per 32-lane group
    int sl = lane & 31;
    int hw = h0 + (wv << 1) + rw;
    float vw0 = virtual_w[h0 + (wv << 1)];
    float vw1 = virtual_w[h0 + (wv << 1) + 1];

    // ---- prefetch row 0 (before the single barrier) ----
    int rowid = rbase;
    int cnt = counts[rowid];
    int2 eA = bins2[rowid * CAP_ + slot];
    int2 eB = bins2[rowid * CAP_ + slot + 32];

    __syncthreads();                 // the ONLY block barrier

    while (rowid < NBIN_) {
        // ---- issue next row's prefetch (independent loads) ----
        int rowid_n = rowid + RSTRIDE_;
        int rn = rowid_n < NBIN_ ? rowid_n : 0;      // safe dummy address
        int cnt_n = counts[rn];
        int2 eA_n = bins2[rn * CAP_ + slot];
        int2 eB_n = bins2[rn * CAP_ + slot + 32];

        int b = rowid / N1_;
        int i = rowid - b * N1_;

        // ---- init wave strip (2 rows) ----
#pragma unroll
        for (int r = 0; r < 2; ++r) {
            float vwr = (r == 0) ? vw0 : vw1;
            float fill = (i == 0) ? vwr : 0.0f;
            float4 f4 = make_float4(fill, fill, fill, fill);
            float4* rp = reinterpret_cast<float4*>(sW + r * STRIDE_);
            for (int c = lane; c < STRIDE_ / 4; c += 64) rp[c] = f4;
        }
        if (i != 0 && lane < 2) {    // virtual column t=0 (disjoint from scatter)
            int hr = h0 + (wv << 1) + lane;
            int off = (4 - ((hr + i) & 3)) & 3;
            sW[lane * STRIDE_ + 4 - off] = (lane == 0) ? vw0 : vw1;
        }

        // ---- gather (wave-private; no barrier) ----
        int c = cnt < CAP_ ? cnt : CAP_;
        int offq = (4 - ((hq + i) & 3)) & 3;
        int base = hh_q * STRIDE_ + 4 - offq;
        if (slot < c) {
            float dist = __int_as_float(eA.y);
            int other = eA.x & 0x1FF;
            int r     = (eA.x >> 9) & 0x7F;
            int lo    = eA.x >> 16;
            float acc = fmaf(dist, sB[lo * TS_ + hhg], sA[lo * TS_ + hhg])
                      + sType[r * TS_ + hhg];
            atomicAdd(&sW[base + other], acc);
        }
        if (slot + 32 < c) {
            float dist = __int_as_float(eB.y);
            int other = eB.x & 0x1FF;
            int r     = (eB.x >> 9) & 0x7F;
            int lo    = eB.x >> 16;
            float acc = fmaf(dist, sB[lo * TS_ + hhg], sA[lo * TS_ + hhg])
                      + sType[r * TS_ + hhg];
            atomicAdd(&sW[base + other], acc);
        }
        for (int j = slot + 64; j < c; j += 32) {    // rare (cnt>64)
            int2 e2 = bins2[rowid * CAP_ + j];
            float dist = __int_as_float(e2.y);
            int other = e2.x & 0x1FF;
            int r     = (e2.x >> 9) & 0x7F;
            int lo    = e2.x >> 16;
            float acc = fmaf(dist, sB[lo * TS_ + hhg], sA[lo * TS_ + hhg])
                      + sType[r * TS_ + hhg];
            atomicAdd(&sW[base + other], acc);
        }

        // ---- writeout (wave-private; per-wave LDS ordering), nontemporal ----
        {
            const float* rr = sW + rw * STRIDE_;
            float* dst = out + ((size_t)(b * H_ + hw)) * PLANE_ + (size_t)i * N1_;
            int off = (4 - ((hw + i) & 3)) & 3;
            if (sl < off) __builtin_nontemporal_store(rr[4 - off + sl], dst + sl);
            int nvec = (N1_ - off) >> 2;            // 95 or 96
            for (int q = sl; q < nvec; q += 32) {   // 3 iterations
                vfloat4 v = *reinterpret_cast<const vfloat4*>(rr + 4 + 4 * q);
                __builtin_nontemporal_store(v,
                    reinterpret_cast<vfloat4*>(dst + off + 4 * q));
            }
            int done = off + (nvec << 2);
            int rem = N1_ - done;                   // 0..3
            if (sl < rem)
                __builtin_nontemporal_store(rr[4 + 4 * nvec + sl], dst + done + sl);
        }

        rowid = rowid_n; cnt = cnt_n; eA = eA_n; eB = eB_n;
    }
}

// ============================================================================
// FALLBACK PATH (round-1, passing): used only if ws_size is too small.
// ============================================================================

__global__ __launch_bounds__(256) void init_out_kernel(
    float* __restrict__ out, const float* __restrict__ virtual_w)
{
    unsigned int tid = blockIdx.x * blockDim.x + threadIdx.x;
    unsigned int base = tid * 4u;
    if (base >= (unsigned int)TOTAL_) return;
    float4 v; float* pv = &v.x;
#pragma unroll
    for (int u = 0; u < 4; ++u) {
        unsigned int idx = base + u;
        unsigned int bh     = idx / (unsigned int)PLANE_;
        unsigned int within = idx - bh * (unsigned int)PLANE_;
        unsigned int h = bh & (H_ - 1);
        unsigned int i = within / (unsigned int)N1_;
        unsigned int j = within - i * (unsigned int)N1_;
        pv[u] = (i == 0u || j == 0u) ? virtual_w[h] : 0.0f;
    }
    *reinterpret_cast<float4*>(out + base) = v;
}

__global__ __launch_bounds__(256) void edge_kernel(
    const float4* __restrict__ edge_feat, const int* __restrict__ edge_index,
    const void* __restrict__ edge_mask, const int* __restrict__ nlig,
    const float* __restrict__ structural_w, const float* __restrict__ plip_protein_w,
    const float* __restrict__ plip_ligand_w, const float* __restrict__ plip_inter_w,
    const float* __restrict__ loc_w, const float* __restrict__ W1,
    const float* __restrict__ b1, const float* __restrict__ W2,
    const float* __restrict__ b2, float* __restrict__ out)
{
    __shared__ float sW2[H_ * H_];
    __shared__ float sW1[H_], sb1[H_], sb2[H_];
    __shared__ float sStruct[20 * H_];
    __shared__ float sPlipP[15 * H_], sPlipL[15 * H_], sPlipI[15 * H_];
    __shared__ float sLoc[4 * H_];

    for (int i = threadIdx.x; i < H_ * H_; i += blockDim.x) sW2[i] = W2[i];
    if (threadIdx.x < H_) {
        sW1[threadIdx.x] = W1[threadIdx.x];
        sb1[threadIdx.x] = b1[threadIdx.x];
        sb2[threadIdx.x] = b2[threadIdx.x];
    }
    for (int i = threadIdx.x; i < 20 * H_; i += blockDim.x) sStruct[i] = structural_w[i];
    for (int i = threadIdx.x; i < 15 * H_; i += blockDim.x) {
        sPlipP[i] = plip_protein_w[i]; sPlipL[i] = plip_ligand_w[i]; sPlipI[i] = plip_inter_w[i];
    }
    for (int i = threadIdx.x; i < 4 * H_; i += blockDim.x) sLoc[i] = loc_w[i];

    int lane = threadIdx.x & 63;
    int probe = ((const int*)edge_mask)[lane];
    bool byte_mask = __any(probe != 0 && probe != 1);
    __syncthreads();

    int gid = blockIdx.x * blockDim.x + threadIdx.x;
    int b = gid >> 13, e = gid & (E_ - 1);
    bool m = byte_mask ? (((const unsigned char*)edge_mask)[gid] != 0)
                       : (((const int*)edge_mask)[gid] != 0);
    if (!m) return;
    int src = edge_index[(b * 2 + 0) * E_ + e];
    int tgt = edge_index[(b * 2 + 1) * E_ + e];
    if (src < 0 || src >= NN_ || tgt < 0 || tgt >= NN_) return;
    if (src == 0 && tgt == 0) return;

    float4 ef = edge_feat[gid];
    int c0 = (int)ef.x, c1 = (int)ef.y, c2 = (int)ef.z;
    float dist = ef.w;
    const float* type_ptr = nullptr; const float* loc_ptr = nullptr;
    if (c0 == 0 || c0 == 1) {
        int si = min(max(c0 * 4 + c1 * 2 + c2, 0), 19);
        type_ptr = &sStruct[si * H_];
    } else if (c0 == 5) {
        int pi = min(max(c1, 0), 14);
        int nl = nlig[b];
        bool sl = src < nl, tl = tgt < nl;
        const float* pw; int loc;
        if (sl && tl)        { pw = sPlipL; loc = 0; }
        else if (!sl && !tl) { pw = sPlipP; loc = 1; }
        else                 { pw = sPlipI; loc = 2; }
        type_ptr = &pw[pi * H_]; loc_ptr = &sLoc[loc * H_];
    }
    float hk[H_];
#pragma unroll
    for (int k = 0; k < H_; ++k) {
        float v = fmaf(dist, sW1[k], sb1[k]);
        hk[k] = v > 0.0f ? v : 0.0f;
    }
    int s1 = src + 1, t1 = tgt + 1;
    float* outb = out + (size_t)b * H_ * PLANE_;
    int off1 = s1 * N1_ + t1, off2 = t1 * N1_ + s1;
#pragma unroll 4
    for (int h = 0; h < H_; ++h) {
        float acc = sb2[h];
#pragma unroll
        for (int k = 0; k < H_; ++k) acc = fmaf(hk[k], sW2[h * H_ + k], acc);
        if (type_ptr) acc += type_ptr[h];
        if (loc_ptr)  acc += loc_ptr[h];
        float* p = outb + (size_t)h * PLANE_;
        unsafeAtomicAdd(p + off1, acc);
        unsafeAtomicAdd(p + off2, acc);
    }
}

// ============================================================================
extern "C" void kernel_launch(void* const* d_in, const int* in_sizes, int n_in,
                              void* d_out, int out_size, void* d_ws, size_t ws_size,
                              hipStream_t stream)
{
    const float4* edge_feat      = (const float4*)d_in[0];
    const int*    edge_index     = (const int*)  d_in[2];
    const void*   edge_mask      =               d_in[3];
    const int*    nlig           = (const int*)  d_in[4];
    const float*  structural_w   = (const float*)d_in[5];
    const float*  plip_protein_w = (const float*)d_in[6];
    const float*  plip_ligand_w  = (const float*)d_in[7];
    const float*  plip_inter_w   = (const float*)d_in[8];
    const float*  loc_w          = (const float*)d_in[9];
    const float*  virtual_w      = (const float*)d_in[10];
    const float*  W1             = (const float*)d_in[11];
    const float*  b1             = (const float*)d_in[12];
    const float*  W2             = (const float*)d_in[13];
    const float*  b2             = (const float*)d_in[14];
    float* out = (float*)d_out;

    if (ws_size >= WS_NEED) {
        char* ws = (char*)d_ws;
        int*   counts = (int*)  (ws + WS_COUNTS);
        float* T      = (float*)(ws + WS_T);
        float* A      = (float*)(ws + WS_A);
        float* Bv     = (float*)(ws + WS_B);
        int2*  bins2  = (int2*) (ws + WS_BINS2);

        prep_kernel<<<25, 256, 0, stream>>>(W1, b1, W2, b2, T, A, Bv, counts);
        bin_kernel<<<(B_ * E_) / 256, 256, 0, stream>>>(
            edge_feat, edge_index, edge_mask, nlig, T, counts, bins2);
        chunk_kernel<<<GBLK_, 512, 0, stream>>>(
            structural_w, plip_protein_w, plip_ligand_w, plip_inter_w,
            loc_w, virtual_w, A, Bv, counts, bins2, out);
    } else {
        unsigned int nth  = (unsigned int)(TOTAL_ / 4);
        unsigned int nblk = (nth + 255u) / 256u;
        init_out_kernel<<<nblk, 256, 0, stream>>>(out, virtual_w);
        edge_kernel<<<(B_ * E_) / 256, 256, 0, stream>>>(
            edge_feat, edge_index, edge_mask, nlig,
            structural_w, plip_protein_w, plip_ligand_w, plip_inter_w,
            loc_w, W1, b1, W2, b2, out);
    }
}

// Round 9
// 95.797 us; speedup vs baseline: 1.5496x; 1.5496x over previous
//
#include <hip/hip_runtime.h>
#include <hip/hip_bf16.h>

#define B_  16
#define E_  8192
#define NN_ 384
#define N1_ 385
#define H_  32
#define HH_ 16                      // h-planes per block (half of H)
#define PLANE_ (N1_ * N1_)          // 148225
#define TOTAL_ (B_ * H_ * PLANE_)   // 75,891,200
#define CAP_ 128                    // bin capacity (avg fill ~38)
#define NBIN_ (B_ * N1_)            // 6160 bins keyed by (b, row_index_1based)
#define STRIDE_ 396                 // LDS row stride: %4==0 (float4-able)
#define TS_ 21                      // table stride: gcd(21,32)=1 -> full bank spread
#define GBLK_ 1024                  // persistent grid: 4 blocks/CU * 256 CU
#define NSPAN_ 512                  // spans per half; 6160 = 512*12 + 16

// workspace layout (bytes)
#define WS_COUNTS 0                           // 6160*4 = 24640
#define WS_T      32768                       // 32*4
#define WS_A      33024                       // 33*32*4 = 4224
#define WS_B      (33024 + 33*32*4)           // ends 41472 < 65536
#define WS_BINS2  65536                       // 6160*128*8 = 6,307,840
#define WS_NEED   ((size_t)WS_BINS2 + (size_t)NBIN_*CAP_*8)   // 6,373,376

// ============================================================================
// FAST PATH
// ============================================================================

// Fused: zero counts (all blocks) + piecewise-linear MLP precompute (block 0).
// f_h(d) = b2_h + sum_k relu(d*W1_k+b1_k)*W2[h][k] is piecewise-linear with
// breakpoints t_k = -b1_k/W1_k; per sorted segment s: f_h(d) = A[s][h]+d*Bv[s][h].
__global__ __launch_bounds__(256) void prep_kernel(
    const float* __restrict__ W1, const float* __restrict__ b1,
    const float* __restrict__ W2, const float* __restrict__ b2,
    float* __restrict__ T, float* __restrict__ A, float* __restrict__ Bv,
    int* __restrict__ counts)
{
    int g = blockIdx.x * 256 + threadIdx.x;
    if (g < NBIN_) counts[g] = 0;

    if (blockIdx.x == 0) {
        __shared__ float sTv[32], sT[32], sW1[32], sb1[32];
        int tid = threadIdx.x;
        if (tid < 32) {
            float w = W1[tid], b = b1[tid];
            sW1[tid] = w; sb1[tid] = b;
            sTv[tid] = (w != 0.0f) ? (-b / w) : -3.402823e38f;
        }
        __syncthreads();
        if (tid < 32) {                 // stable rank sort
            float t = sTv[tid];
            int rank = 0;
            for (int j = 0; j < 32; ++j) {
                float tj = sTv[j];
                rank += (tj < t || (tj == t && j < tid)) ? 1 : 0;
            }
            sT[rank] = t;
        }
        __syncthreads();
        if (tid < 32) T[tid] = sT[tid];
        for (int idx = tid; idx < 33 * 32; idx += 256) {
            int s = idx >> 5, h = idx & 31;
            float m;
            if (s == 0)       m = sT[0] - 1.0f;
            else if (s == 32) m = sT[31] + 1.0f;
            else              m = 0.5f * (sT[s - 1] + sT[s]);
            float alpha = b2[h], beta = 0.0f;
            for (int k = 0; k < 32; ++k) {
                float w = sW1[k], b = sb1[k];
                bool act = (w > 0.0f) ? (m > -b / w)
                         : (w < 0.0f) ? (m < -b / w) : (b > 0.0f);
                if (act) {
                    float w2 = W2[h * 32 + k];
                    alpha = fmaf(w2, b, alpha);
                    beta  = fmaf(w2, w, beta);
                }
            }
            A[idx] = alpha; Bv[idx] = beta;
        }
    }
}

// Per valid edge: push entry into both endpoint bins.
// meta = (lo<<16) | (r<<9) | other;  lo = dist's PL segment, r = type row,
// other = opposite endpoint (1-based). dist stored alongside.
__global__ __launch_bounds__(256) void bin_kernel(
    const float4* __restrict__ edge_feat,   // (B,E,4)
    const int*    __restrict__ edge_index,  // (B,2,E)
    const void*   __restrict__ edge_mask,   // (B,E) bool(1B) or int32 — detected
    const int*    __restrict__ nlig,        // (B,)
    const float*  __restrict__ T,           // (32) sorted breakpoints
    int* __restrict__ counts, int2* __restrict__ bins2)
{
    int lane = threadIdx.x & 63;
    int probe = ((const int*)edge_mask)[lane];
    bool byte_mask = __any(probe != 0 && probe != 1);

    int gid = blockIdx.x * blockDim.x + threadIdx.x;   // exact grid: B*E
    int b = gid >> 13, e = gid & (E_ - 1);
    bool m = byte_mask ? (((const unsigned char*)edge_mask)[gid] != 0)
                       : (((const int*)edge_mask)[gid] != 0);
    if (!m) return;
    int src = edge_index[(b * 2 + 0) * E_ + e];
    int tgt = edge_index[(b * 2 + 1) * E_ + e];
    if (src < 0 || src >= NN_ || tgt < 0 || tgt >= NN_) return;
    if (src == 0 && tgt == 0) return;

    float4 ef = edge_feat[gid];
    int c0 = (int)ef.x, c1 = (int)ef.y, c2 = (int)ef.z;
    float dist = ef.w;

    int r;
    if (c0 == 0 || c0 == 1) {
        r = min(max(c0 * 4 + c1 * 2 + c2, 0), 19);
    } else if (c0 == 5) {
        int pi = min(max(c1, 0), 14);
        int nl = nlig[b];
        bool sl = src < nl, tl = tgt < nl;
        int loc = (sl && tl) ? 0 : ((!sl && !tl) ? 1 : 2);
        r = 20 + loc * 15 + pi;
    } else r = 65;   // zero row

    // segment index: #{T[k] < dist}
    int lo = 0;
#pragma unroll
    for (int q = 0; q < 8; ++q) {
        float4 tv = *reinterpret_cast<const float4*>(T + 4 * q);
        lo += (tv.x < dist) ? 1 : 0;
        lo += (tv.y < dist) ? 1 : 0;
        lo += (tv.z < dist) ? 1 : 0;
        lo += (tv.w < dist) ? 1 : 0;
    }

    int s1 = src + 1, t1 = tgt + 1;
    int db = __float_as_int(dist);
    int base = (lo << 16) | (r << 9);
    int bin1 = b * N1_ + s1, bin2i = b * N1_ + t1;
    int p = atomicAdd(&counts[bin1], 1);
    if (p < CAP_) bins2[bin1 * CAP_ + p] = make_int2(base | t1, db);
    p = atomicAdd(&counts[bin2i], 1);
    if (p < CAP_) bins2[bin2i * CAP_ + p] = make_int2(base | s1, db);
}

// Persistent grid: 1024 blocks (4/CU); block = (h-half, span of 12-13
// CONTIGUOUS rows). 512 threads = 8 waves; each WAVE owns 2 h-planes
// (wave-private LDS strip) -> no barriers in the row loop. Scalar count
// prefetched one row ahead. LDS rows are SHIFTED: column t lives at
// (4-off)+t, off=(4-((h+i)&3))&3, so LDS float4 and global dwordx4
// accesses are both 16B-aligned.
__global__ __launch_bounds__(512, 8) void chunk_kernel(
    const float* __restrict__ structural_w,   // (20,H)
    const float* __restrict__ plip_protein_w, // (15,H)
    const float* __restrict__ plip_ligand_w,  // (15,H)
    const float* __restrict__ plip_inter_w,   // (15,H)
    const float* __restrict__ loc_w,          // (4,H)
    const float* __restrict__ virtual_w,      // (1,H)
    const float* __restrict__ A,              // (33,32)
    const float* __restrict__ Bv,             // (33,32)
    const int*   __restrict__ counts,         // (NBIN_)
    const int2*  __restrict__ bins2,          // (NBIN_,CAP_)
    float* __restrict__ out)                  // (B,H,N1,N1)
{
    __shared__ float4 srow4[HH_ * (STRIDE_ / 4)];   // 25344 B; wave w owns rows 2w,2w+1
    __shared__ float sA[33 * TS_], sB[33 * TS_];    // 2772 B each
    __shared__ float sType[66 * TS_];               // 5544 B
    float* srow = reinterpret_cast<float*>(srow4);

    int bid = blockIdx.x;
    int half = bid & 1;
    int idx  = bid >> 1;             // span index 0..511
    int h0 = half << 4;
    int tid = threadIdx.x;
    int wv = tid >> 6, lane = tid & 63;

    // contiguous span: 6160 = 512*12 + 16 -> first 16 spans have 13 rows
    int start = idx * 12 + min(idx, 16);
    int len   = 12 + (idx < 16 ? 1 : 0);

    // ---- stage tables (once per block) ----
    for (int idx2 = tid; idx2 < 33 * 16; idx2 += 512) {
        int s = idx2 >> 4, hh = idx2 & 15;
        sA[s * TS_ + hh] = A[s * 32 + h0 + hh];
        sB[s * TS_ + hh] = Bv[s * 32 + h0 + hh];
    }
    for (int idx2 = tid; idx2 < 66 * 16; idx2 += 512) {
        int r = idx2 >> 4, hh = idx2 & 15;
        float v;
        if (r < 20) v = structural_w[r * 32 + h0 + hh];
        else if (r < 65) {
            int t2 = r - 20;
            int loc = t2 / 15, pi = t2 - loc * 15;
            const float* pw = (loc == 0) ? plip_ligand_w
                            : (loc == 1) ? plip_protein_w : plip_inter_w;
            v = pw[pi * 32 + h0 + hh] + loc_w[loc * 32 + h0 + hh];
        } else v = 0.0f;
        sType[r * TS_ + hh] = v;
    }

    int hh_q = lane & 1;             // plane within wave's pair
    int slot = lane >> 1;            // entry slot 0..31
    int hhg  = (wv << 1) | hh_q;     // hh within half, 0..15
    int hq   = h0 + hhg;             // global h for gather lane
    float* sW = srow + (wv << 1) * STRIDE_;   // wave-private strip (2 rows)

    int rw = lane >> 5;              // writeout: plane 0..1 per 32-lane group
    int sl = lane & 31;
    int hw = h0 + (wv << 1) + rw;
    float vw0 = virtual_w[h0 + (wv << 1)];
    float vw1 = virtual_w[h0 + (wv << 1) + 1];

    int cnt = counts[start];         // prefetch first row's count
    __syncthreads();                 // the ONLY block barrier

#pragma unroll 1
    for (int ii = 0; ii < len; ++ii) {
        int rowid = start + ii;
        int rn = rowid + 1 < NBIN_ ? rowid + 1 : NBIN_ - 1;
        int cnt_n = counts[rn];      // next row's count (hidden under this row)

        int b = rowid / N1_;
        int i = rowid - b * N1_;

        // ---- init wave strip (2 rows) ----
#pragma unroll
        for (int r = 0; r < 2; ++r) {
            float vwr = (r == 0) ? vw0 : vw1;
            float fill = (i == 0) ? vwr : 0.0f;
            float4 f4 = make_float4(fill, fill, fill, fill);
            float4* rp = reinterpret_cast<float4*>(sW + r * STRIDE_);
            for (int c = lane; c < STRIDE_ / 4; c += 64) rp[c] = f4;
        }
        if (i != 0 && lane < 2) {    // virtual column t=0 (disjoint from scatter)
            int hr = h0 + (wv << 1) + lane;
            int off = (4 - ((hr + i) & 3)) & 3;
            sW[lane * STRIDE_ + 4 - off] = (lane == 0) ? vw0 : vw1;
        }

        // ---- gather (wave-private; no barrier) ----
        int c = cnt < CAP_ ? cnt : CAP_;
        int offq = (4 - ((hq + i) & 3)) & 3;
        int base = hh_q * STRIDE_ + 4 - offq;
        for (int j = slot; j < c; j += 32) {
            int2 e2 = bins2[rowid * CAP_ + j];
            float dist = __int_as_float(e2.y);
            int other = e2.x & 0x1FF;
            int r     = (e2.x >> 9) & 0x7F;
            int lo    = e2.x >> 16;
            float acc = fmaf(dist, sB[lo * TS_ + hhg], sA[lo * TS_ + hhg])
                      + sType[r * TS_ + hhg];
            atomicAdd(&sW[base + other], acc);
        }

        // ---- writeout (wave-private; per-wave LDS ordering) ----
        {
            const float* rr = sW + rw * STRIDE_;
            float* dst = out + ((size_t)(b * H_ + hw)) * PLANE_ + (size_t)i * N1_;
            int off = (4 - ((hw + i) & 3)) & 3;
            if (sl < off) dst[sl] = rr[4 - off + sl];
            int nvec = (N1_ - off) >> 2;            // 95 or 96
            for (int q = sl; q < nvec; q += 32) {   // 3 iterations
                float4 v = *reinterpret_cast<const float4*>(rr + 4 + 4 * q);
                *reinterpret_cast<float4*>(dst + off + 4 * q) = v;
            }
            int done = off + (nvec << 2);
            int rem = N1_ - done;                   // 0..3
            if (sl < rem) dst[done + sl] = rr[4 + 4 * nvec + sl];
        }

        cnt = cnt_n;
    }
}

// ============================================================================
// FALLBACK PATH (round-1, passing): used only if ws_size is too small.
// ============================================================================

__global__ __launch_bounds__(256) void init_out_kernel(
    float* __restrict__ out, const float* __restrict__ virtual_w)
{
    unsigned int tid = blockIdx.x * blockDim.x + threadIdx.x;
    unsigned int base = tid * 4u;
    if (base >= (unsigned int)TOTAL_) return;
    float4 v; float* pv = &v.x;
#pragma unroll
    for (int u = 0; u < 4; ++u) {
        unsigned int idx = base + u;
        unsigned int bh     = idx / (unsigned int)PLANE_;
        unsigned int within = idx - bh * (unsigned int)PLANE_;
        unsigned int h = bh & (H_ - 1);
        unsigned int i = within / (unsigned int)N1_;
        unsigned int j = within - i * (unsigned int)N1_;
        pv[u] = (i == 0u || j == 0u) ? virtual_w[h] : 0.0f;
    }
    *reinterpret_cast<float4*>(out + base) = v;
}

__global__ __launch_bounds__(256) void edge_kernel(
    const float4* __restrict__ edge_feat, const int* __restrict__ edge_index,
    const void* __restrict__ edge_mask, const int* __restrict__ nlig,
    const float* __restrict__ structural_w, const float* __restrict__ plip_protein_w,
    const float* __restrict__ plip_ligand_w, const float* __restrict__ plip_inter_w,
    const float* __restrict__ loc_w, const float* __restrict__ W1,
    const float* __restrict__ b1, const float* __restrict__ W2,
    const float* __restrict__ b2, float* __restrict__ out)
{
    __shared__ float sW2[H_ * H_];
    __shared__ float sW1[H_], sb1[H_], sb2[H_];
    __shared__ float sStruct[20 * H_];
    __shared__ float sPlipP[15 * H_], sPlipL[15 * H_], sPlipI[15 * H_];
    __shared__ float sLoc[4 * H_];

    for (int i = threadIdx.x; i < H_ * H_; i += blockDim.x) sW2[i] = W2[i];
    if (threadIdx.x < H_) {
        sW1[threadIdx.x] = W1[threadIdx.x];
        sb1[threadIdx.x] = b1[threadIdx.x];
        sb2[threadIdx.x] = b2[threadIdx.x];
    }
    for (int i = threadIdx.x; i < 20 * H_; i += blockDim.x) sStruct[i] = structural_w[i];
    for (int i = threadIdx.x; i < 15 * H_; i += blockDim.x) {
        sPlipP[i] = plip_protein_w[i]; sPlipL[i] = plip_ligand_w[i]; sPlipI[i] = plip_inter_w[i];
    }
    for (int i = threadIdx.x; i < 4 * H_; i += blockDim.x) sLoc[i] = loc_w[i];

    int lane = threadIdx.x & 63;
    int probe = ((const int*)edge_mask)[lane];
    bool byte_mask = __any(probe != 0 && probe != 1);
    __syncthreads();

    int gid = blockIdx.x * blockDim.x + threadIdx.x;
    int b = gid >> 13, e = gid & (E_ - 1);
    bool m = byte_mask ? (((const unsigned char*)edge_mask)[gid] != 0)
                       : (((const int*)edge_mask)[gid] != 0);
    if (!m) return;
    int src = edge_index[(b * 2 + 0) * E_ + e];
    int tgt = edge_index[(b * 2 + 1) * E_ + e];
    if (src < 0 || src >= NN_ || tgt < 0 || tgt >= NN_) return;
    if (src == 0 && tgt == 0) return;

    float4 ef = edge_feat[gid];
    int c0 = (int)ef.x, c1 = (int)ef.y, c2 = (int)ef.z;
    float dist = ef.w;
    const float* type_ptr = nullptr; const float* loc_ptr = nullptr;
    if (c0 == 0 || c0 == 1) {
        int si = min(max(c0 * 4 + c1 * 2 + c2, 0), 19);
        type_ptr = &sStruct[si * H_];
    } else if (c0 == 5) {
        int pi = min(max(c1, 0), 14);
        int nl = nlig[b];
        bool sl = src < nl, tl = tgt < nl;
        const float* pw; int loc;
        if (sl && tl)        { pw = sPlipL; loc = 0; }
        else if (!sl && !tl) { pw = sPlipP; loc = 1; }
        else                 { pw = sPlipI; loc = 2; }
        type_ptr = &pw[pi * H_]; loc_ptr = &sLoc[loc * H_];
    }
    float hk[H_];
#pragma unroll
    for (int k = 0; k < H_; ++k) {
        float v = fmaf(dist, sW1[k], sb1[k]);
        hk[k] = v > 0.0f ? v : 0.0f;
    }
    int s1 = src + 1, t1 = tgt + 1;
    float* outb = out + (size_t)b * H_ * PLANE_;
    int off1 = s1 * N1_ + t1, off2 = t1 * N1_ + s1;
#pragma unroll 4
    for (int h = 0; h < H_; ++h) {
        float acc = sb2[h];
#pragma unroll
        for (int k = 0; k < H_; ++k) acc = fmaf(hk[k], sW2[h * H_ + k], acc);
        if (type_ptr) acc += type_ptr[h];
        if (loc_ptr)  acc += loc_ptr[h];
        float* p = outb + (size_t)h * PLANE_;
        unsafeAtomicAdd(p + off1, acc);
        unsafeAtomicAdd(p + off2, acc);
    }
}

// ============================================================================
extern "C" void kernel_launch(void* const* d_in, const int* in_sizes, int n_in,
                              void* d_out, int out_size, void* d_ws, size_t ws_size,
                              hipStream_t stream)
{
    const float4* edge_feat      = (const float4*)d_in[0];
    const int*    edge_index     = (const int*)  d_in[2];
    const void*   edge_mask      =               d_in[3];
    const int*    nlig           = (const int*)  d_in[4];
    const float*  structural_w   = (const float*)d_in[5];
    const float*  plip_protein_w = (const float*)d_in[6];
    const float*  plip_ligand_w  = (const float*)d_in[7];
    const float*  plip_inter_w   = (const float*)d_in[8];
    const float*  loc_w          = (const float*)d_in[9];
    const float*  virtual_w      = (const float*)d_in[10];
    const float*  W1             = (const float*)d_in[11];
    const float*  b1             = (const float*)d_in[12];
    const float*  W2             = (const float*)d_in[13];
    const float*  b2             = (const float*)d_in[14];
    float* out = (float*)d_out;

    if (ws_size >= WS_NEED) {
        char* ws = (char*)d_ws;
        int*   counts = (int*)  (ws + WS_COUNTS);
        float* T      = (float*)(ws + WS_T);
        float* A      = (float*)(ws + WS_A);
        float* Bv     = (float*)(ws + WS_B);
        int2*  bins2  = (int2*) (ws + WS_BINS2);

        prep_kernel<<<25, 256, 0, stream>>>(W1, b1, W2, b2, T, A, Bv, counts);
        bin_kernel<<<(B_ * E_) / 256, 256, 0, stream>>>(
            edge_feat, edge_index, edge_mask, nlig, T, counts, bins2);
        chunk_kernel<<<GBLK_, 512, 0, stream>>>(
            structural_w, plip_protein_w, plip_ligand_w, plip_inter_w,
            loc_w, virtual_w, A, Bv, counts, bins2, out);
    } else {
        unsigned int nth  = (unsigned int)(TOTAL_ / 4);
        unsigned int nblk = (nth + 255u) / 256u;
        init_out_kernel<<<nblk, 256, 0, stream>>>(out, virtual_w);
        edge_kernel<<<(B_ * E_) / 256, 256, 0, stream>>>(
            edge_feat, edge_index, edge_mask, nlig,
            structural_w, plip_protein_w, plip_ligand_w, plip_inter_w,
            loc_w, W1, b1, W2, b2, out);
    }
}

// Round 10
// 95.166 us; speedup vs baseline: 1.5599x; 1.0066x over previous
//
#include <hip/hip_runtime.h>
#include <hip/hip_bf16.h>

#define B_  16
#define E_  8192
#define NN_ 384
#define N1_ 385
#define H_  32
#define HH_ 16                      // h-planes per block (half of H)
#define PLANE_ (N1_ * N1_)          // 148225
#define TOTAL_ (B_ * H_ * PLANE_)   // 75,891,200
#define CAP_ 128                    // bin capacity (avg fill ~38)
#define NBIN_ (B_ * N1_)            // 6160 bins keyed by (b, row_index_1based)
#define STRIDE_ 396                 // LDS row stride: %4==0 (float4-able)
#define TS_ 21                      // table stride: gcd(21,32)=1 -> full bank spread
#define GBLK_ 1024                  // persistent grid: 4 blocks/CU * 256 CU
#define NSPAN_ 512                  // spans per half; 6160 = 512*12 + 16

// workspace layout (bytes)
#define WS_COUNTS 0                           // 6160*4 = 24640
#define WS_T      32768                       // 32*4
#define WS_A      33024                       // 33*32*4 = 4224
#define WS_B      (33024 + 33*32*4)           // ends 41472 < 65536
#define WS_BINS2  65536                       // 6160*128*8 = 6,307,840
#define WS_NEED   ((size_t)WS_BINS2 + (size_t)NBIN_*CAP_*8)   // 6,373,376

// ============================================================================
// FAST PATH
// ============================================================================

// Fused: zero counts (all blocks) + piecewise-linear MLP precompute (block 0).
// f_h(d) = b2_h + sum_k relu(d*W1_k+b1_k)*W2[h][k] is piecewise-linear with
// breakpoints t_k = -b1_k/W1_k; per sorted segment s: f_h(d) = A[s][h]+d*Bv[s][h].
__global__ __launch_bounds__(256) void prep_kernel(
    const float* __restrict__ W1, const float* __restrict__ b1,
    const float* __restrict__ W2, const float* __restrict__ b2,
    float* __restrict__ T, float* __restrict__ A, float* __restrict__ Bv,
    int* __restrict__ counts)
{
    int g = blockIdx.x * 256 + threadIdx.x;
    if (g < NBIN_) counts[g] = 0;

    if (blockIdx.x == 0) {
        __shared__ float sTv[32], sT[32], sW1[32], sb1[32];
        int tid = threadIdx.x;
        if (tid < 32) {
            float w = W1[tid], b = b1[tid];
            sW1[tid] = w; sb1[tid] = b;
            sTv[tid] = (w != 0.0f) ? (-b / w) : -3.402823e38f;
        }
        __syncthreads();
        if (tid < 32) {                 // stable rank sort
            float t = sTv[tid];
            int rank = 0;
            for (int j = 0; j < 32; ++j) {
                float tj = sTv[j];
                rank += (tj < t || (tj == t && j < tid)) ? 1 : 0;
            }
            sT[rank] = t;
        }
        __syncthreads();
        if (tid < 32) T[tid] = sT[tid];
        for (int idx = tid; idx < 33 * 32; idx += 256) {
            int s = idx >> 5, h = idx & 31;
            float m;
            if (s == 0)       m = sT[0] - 1.0f;
            else if (s == 32) m = sT[31] + 1.0f;
            else              m = 0.5f * (sT[s - 1] + sT[s]);
            float alpha = b2[h], beta = 0.0f;
            for (int k = 0; k < 32; ++k) {
                float w = sW1[k], b = sb1[k];
                bool act = (w > 0.0f) ? (m > -b / w)
                         : (w < 0.0f) ? (m < -b / w) : (b > 0.0f);
                if (act) {
                    float w2 = W2[h * 32 + k];
                    alpha = fmaf(w2, b, alpha);
                    beta  = fmaf(w2, w, beta);
                }
            }
            A[idx] = alpha; Bv[idx] = beta;
        }
    }
}

// Per valid edge: push entry into both endpoint bins.
// meta = (lo<<16) | (r<<9) | other;  lo = dist's PL segment, r = type row,
// other = opposite endpoint (1-based). dist stored alongside.
__global__ __launch_bounds__(256) void bin_kernel(
    const float4* __restrict__ edge_feat,   // (B,E,4)
    const int*    __restrict__ edge_index,  // (B,2,E)
    const void*   __restrict__ edge_mask,   // (B,E) bool(1B) or int32 — detected
    const int*    __restrict__ nlig,        // (B,)
    const float*  __restrict__ T,           // (32) sorted breakpoints
    int* __restrict__ counts, int2* __restrict__ bins2)
{
    int lane = threadIdx.x & 63;
    int probe = ((const int*)edge_mask)[lane];
    bool byte_mask = __any(probe != 0 && probe != 1);

    int gid = blockIdx.x * blockDim.x + threadIdx.x;   // exact grid: B*E
    int b = gid >> 13, e = gid & (E_ - 1);
    bool m = byte_mask ? (((const unsigned char*)edge_mask)[gid] != 0)
                       : (((const int*)edge_mask)[gid] != 0);
    if (!m) return;
    int src = edge_index[(b * 2 + 0) * E_ + e];
    int tgt = edge_index[(b * 2 + 1) * E_ + e];
    if (src < 0 || src >= NN_ || tgt < 0 || tgt >= NN_) return;
    if (src == 0 && tgt == 0) return;

    float4 ef = edge_feat[gid];
    int c0 = (int)ef.x, c1 = (int)ef.y, c2 = (int)ef.z;
    float dist = ef.w;

    int r;
    if (c0 == 0 || c0 == 1) {
        r = min(max(c0 * 4 + c1 * 2 + c2, 0), 19);
    } else if (c0 == 5) {
        int pi = min(max(c1, 0), 14);
        int nl = nlig[b];
        bool sl = src < nl, tl = tgt < nl;
        int loc = (sl && tl) ? 0 : ((!sl && !tl) ? 1 : 2);
        r = 20 + loc * 15 + pi;
    } else r = 65;   // zero row

    // segment index: #{T[k] < dist}
    int lo = 0;
#pragma unroll
    for (int q = 0; q < 8; ++q) {
        float4 tv = *reinterpret_cast<const float4*>(T + 4 * q);
        lo += (tv.x < dist) ? 1 : 0;
        lo += (tv.y < dist) ? 1 : 0;
        lo += (tv.z < dist) ? 1 : 0;
        lo += (tv.w < dist) ? 1 : 0;
    }

    int s1 = src + 1, t1 = tgt + 1;
    int db = __float_as_int(dist);
    int base = (lo << 16) | (r << 9);
    int bin1 = b * N1_ + s1, bin2i = b * N1_ + t1;
    int p = atomicAdd(&counts[bin1], 1);
    if (p < CAP_) bins2[bin1 * CAP_ + p] = make_int2(base | t1, db);
    p = atomicAdd(&counts[bin2i], 1);
    if (p < CAP_) bins2[bin2i * CAP_ + p] = make_int2(base | s1, db);
}

// Persistent grid: 1024 blocks (4/CU); block = (h-half, span of 12-13
// CONTIGUOUS rows). 512 threads = 8 waves; each WAVE owns 2 h-planes
// (wave-private LDS strip) -> no barriers in the row loop. Next row's
// count AND first 32-entry bin batch are prefetched into registers
// (minimal prefetch: 1 int2, to stay under the 64-VGPR / 8-wave cap).
// LDS rows are SHIFTED: column t lives at (4-off)+t, off=(4-((h+i)&3))&3,
// so LDS float4 and global dwordx4 accesses are both 16B-aligned.
__global__ __launch_bounds__(512, 8) void chunk_kernel(
    const float* __restrict__ structural_w,   // (20,H)
    const float* __restrict__ plip_protein_w, // (15,H)
    const float* __restrict__ plip_ligand_w,  // (15,H)
    const float* __restrict__ plip_inter_w,   // (15,H)
    const float* __restrict__ loc_w,          // (4,H)
    const float* __restrict__ virtual_w,      // (1,H)
    const float* __restrict__ A,              // (33,32)
    const float* __restrict__ Bv,             // (33,32)
    const int*   __restrict__ counts,         // (NBIN_)
    const int2*  __restrict__ bins2,          // (NBIN_,CAP_)
    float* __restrict__ out)                  // (B,H,N1,N1)
{
    __shared__ float4 srow4[HH_ * (STRIDE_ / 4)];   // 25344 B; wave w owns rows 2w,2w+1
    __shared__ float sA[33 * TS_], sB[33 * TS_];    // 2772 B each
    __shared__ float sType[66 * TS_];               // 5544 B
    float* srow = reinterpret_cast<float*>(srow4);

    int bid = blockIdx.x;
    int half = bid & 1;
    int idx  = bid >> 1;             // span index 0..511
    int h0 = half << 4;
    int tid = threadIdx.x;
    int wv = tid >> 6, lane = tid & 63;

    // contiguous span: 6160 = 512*12 + 16 -> first 16 spans have 13 rows
    int start = idx * 12 + min(idx, 16);
    int len   = 12 + (idx < 16 ? 1 : 0);

    // ---- stage tables (once per block) ----
    for (int idx2 = tid; idx2 < 33 * 16; idx2 += 512) {
        int s = idx2 >> 4, hh = idx2 & 15;
        sA[s * TS_ + hh] = A[s * 32 + h0 + hh];
        sB[s * TS_ + hh] = Bv[s * 32 + h0 + hh];
    }
    for (int idx2 = tid; idx2 < 66 * 16; idx2 += 512) {
        int r = idx2 >> 4, hh = idx2 & 15;
        float v;
        if (r < 20) v = structural_w[r * 32 + h0 + hh];
        else if (r < 65) {
            int t2 = r - 20;
            int loc = t2 / 15, pi = t2 - loc * 15;
            const float* pw = (loc == 0) ? plip_ligand_w
                            : (loc == 1) ? plip_protein_w : plip_inter_w;
            v = pw[pi * 32 + h0 + hh] + loc_w[loc * 32 + h0 + hh];
        } else v = 0.0f;
        sType[r * TS_ + hh] = v;
    }

    int hh_q = lane & 1;             // plane within wave's pair
    int slot = lane >> 1;            // entry slot 0..31
    int hhg  = (wv << 1) | hh_q;     // hh within half, 0..15
    int hq   = h0 + hhg;             // global h for gather lane
    float* sW = srow + (wv << 1) * STRIDE_;   // wave-private strip (2 rows)

    int rw = lane >> 5;              // writeout: plane 0..1 per 32-lane group
    int sl = lane & 31;
    int hw = h0 + (wv << 1) + rw;
    float vw0 = virtual_w[h0 + (wv << 1)];
    float vw1 = virtual_w[h0 + (wv << 1) + 1];

    // ---- prefetch row 0: count + first 32-entry batch ----
    int cnt = counts[start];
    int2 eA = bins2[start * CAP_ + slot];
    __syncthreads();                 // the ONLY block barrier

#pragma unroll 1
    for (int ii = 0; ii < len; ++ii) {
        int rowid = start + ii;
        int rn = rowid + 1 < NBIN_ ? rowid + 1 : NBIN_ - 1;
        int cnt_n = counts[rn];              // next row (hidden under this row)
        int2 eA_n = bins2[rn * CAP_ + slot];

        int b = rowid / N1_;
        int i = rowid - b * N1_;

        // ---- init wave strip (2 rows) ----
#pragma unroll
        for (int r = 0; r < 2; ++r) {
            float vwr = (r == 0) ? vw0 : vw1;
            float fill = (i == 0) ? vwr : 0.0f;
            float4 f4 = make_float4(fill, fill, fill, fill);
            float4* rp = reinterpret_cast<float4*>(sW + r * STRIDE_);
            for (int c = lane; c < STRIDE_ / 4; c += 64) rp[c] = f4;
        }
        if (i != 0 && lane < 2) {    // virtual column t=0 (disjoint from scatter)
            int hr = h0 + (wv << 1) + lane;
            int off = (4 - ((hr + i) & 3)) & 3;
            sW[lane * STRIDE_ + 4 - off] = (lane == 0) ? vw0 : vw1;
        }

        // ---- gather (wave-private; no barrier) ----
        int c = cnt < CAP_ ? cnt : CAP_;
        int offq = (4 - ((hq + i) & 3)) & 3;
        int base = hh_q * STRIDE_ + 4 - offq;
        if (slot < c) {                       // first batch: from registers
            float dist = __int_as_float(eA.y);
            int other = eA.x & 0x1FF;
            int r     = (eA.x >> 9) & 0x7F;
            int lo    = eA.x >> 16;
            float acc = fmaf(dist, sB[lo * TS_ + hhg], sA[lo * TS_ + hhg])
                      + sType[r * TS_ + hhg];
            atomicAdd(&sW[base + other], acc);
        }
        for (int j = slot + 32; j < c; j += 32) {   // overflow batches (~20% lanes)
            int2 e2 = bins2[rowid * CAP_ + j];
            float dist = __int_as_float(e2.y);
            int other = e2.x & 0x1FF;
            int r     = (e2.x >> 9) & 0x7F;
            int lo    = e2.x >> 16;
            float acc = fmaf(dist, sB[lo * TS_ + hhg], sA[lo * TS_ + hhg])
                      + sType[r * TS_ + hhg];
            atomicAdd(&sW[base + other], acc);
        }

        // ---- writeout (wave-private; per-wave LDS ordering) ----
        {
            const float* rr = sW + rw * STRIDE_;
            float* dst = out + ((size_t)(b * H_ + hw)) * PLANE_ + (size_t)i * N1_;
            int off = (4 - ((hw + i) & 3)) & 3;
            if (sl < off) dst[sl] = rr[4 - off + sl];
            int nvec = (N1_ - off) >> 2;            // 95 or 96
            for (int q = sl; q < nvec; q += 32) {   // 3 iterations
                float4 v = *reinterpret_cast<const float4*>(rr + 4 + 4 * q);
                *reinterpret_cast<float4*>(dst + off + 4 * q) = v;
            }
            int done = off + (nvec << 2);
            int rem = N1_ - done;                   // 0..3
            if (sl < rem) dst[done + sl] = rr[4 + 4 * nvec + sl];
        }

        cnt = cnt_n; eA = eA_n;
    }
}

// ============================================================================
// FALLBACK PATH (round-1, passing): used only if ws_size is too small.
// ============================================================================

__global__ __launch_bounds__(256) void init_out_kernel(
    float* __restrict__ out, const float* __restrict__ virtual_w)
{
    unsigned int tid = blockIdx.x * blockDim.x + threadIdx.x;
    unsigned int base = tid * 4u;
    if (base >= (unsigned int)TOTAL_) return;
    float4 v; float* pv = &v.x;
#pragma unroll
    for (int u = 0; u < 4; ++u) {
        unsigned int idx = base + u;
        unsigned int bh     = idx / (unsigned int)PLANE_;
        unsigned int within = idx - bh * (unsigned int)PLANE_;
        unsigned int h = bh & (H_ - 1);
        unsigned int i = within / (unsigned int)N1_;
        unsigned int j = within - i * (unsigned int)N1_;
        pv[u] = (i == 0u || j == 0u) ? virtual_w[h] : 0.0f;
    }
    *reinterpret_cast<float4*>(out + base) = v;
}

__global__ __launch_bounds__(256) void edge_kernel(
    const float4* __restrict__ edge_feat, const int* __restrict__ edge_index,
    const void* __restrict__ edge_mask, const int* __restrict__ nlig,
    const float* __restrict__ structural_w, const float* __restrict__ plip_protein_w,
    const float* __restrict__ plip_ligand_w, const float* __restrict__ plip_inter_w,
    const float* __restrict__ loc_w, const float* __restrict__ W1,
    const float* __restrict__ b1, const float* __restrict__ W2,
    const float* __restrict__ b2, float* __restrict__ out)
{
    __shared__ float sW2[H_ * H_];
    __shared__ float sW1[H_], sb1[H_], sb2[H_];
    __shared__ float sStruct[20 * H_];
    __shared__ float sPlipP[15 * H_], sPlipL[15 * H_], sPlipI[15 * H_];
    __shared__ float sLoc[4 * H_];

    for (int i = threadIdx.x; i < H_ * H_; i += blockDim.x) sW2[i] = W2[i];
    if (threadIdx.x < H_) {
        sW1[threadIdx.x] = W1[threadIdx.x];
        sb1[threadIdx.x] = b1[threadIdx.x];
        sb2[threadIdx.x] = b2[threadIdx.x];
    }
    for (int i = threadIdx.x; i < 20 * H_; i += blockDim.x) sStruct[i] = structural_w[i];
    for (int i = threadIdx.x; i < 15 * H_; i += blockDim.x) {
        sPlipP[i] = plip_protein_w[i]; sPlipL[i] = plip_ligand_w[i]; sPlipI[i] = plip_inter_w[i];
    }
    for (int i = threadIdx.x; i < 4 * H_; i += blockDim.x) sLoc[i] = loc_w[i];

    int lane = threadIdx.x & 63;
    int probe = ((const int*)edge_mask)[lane];
    bool byte_mask = __any(probe != 0 && probe != 1);
    __syncthreads();

    int gid = blockIdx.x * blockDim.x + threadIdx.x;
    int b = gid >> 13, e = gid & (E_ - 1);
    bool m = byte_mask ? (((const unsigned char*)edge_mask)[gid] != 0)
                       : (((const int*)edge_mask)[gid] != 0);
    if (!m) return;
    int src = edge_index[(b * 2 + 0) * E_ + e];
    int tgt = edge_index[(b * 2 + 1) * E_ + e];
    if (src < 0 || src >= NN_ || tgt < 0 || tgt >= NN_) return;
    if (src == 0 && tgt == 0) return;

    float4 ef = edge_feat[gid];
    int c0 = (int)ef.x, c1 = (int)ef.y, c2 = (int)ef.z;
    float dist = ef.w;
    const float* type_ptr = nullptr; const float* loc_ptr = nullptr;
    if (c0 == 0 || c0 == 1) {
        int si = min(max(c0 * 4 + c1 * 2 + c2, 0), 19);
        type_ptr = &sStruct[si * H_];
    } else if (c0 == 5) {
        int pi = min(max(c1, 0), 14);
        int nl = nlig[b];
        bool sl = src < nl, tl = tgt < nl;
        const float* pw; int loc;
        if (sl && tl)        { pw = sPlipL; loc = 0; }
        else if (!sl && !tl) { pw = sPlipP; loc = 1; }
        else                 { pw = sPlipI; loc = 2; }
        type_ptr = &pw[pi * H_]; loc_ptr = &sLoc[loc * H_];
    }
    float hk[H_];
#pragma unroll
    for (int k = 0; k < H_; ++k) {
        float v = fmaf(dist, sW1[k], sb1[k]);
        hk[k] = v > 0.0f ? v : 0.0f;
    }
    int s1 = src + 1, t1 = tgt + 1;
    float* outb = out + (size_t)b * H_ * PLANE_;
    int off1 = s1 * N1_ + t1, off2 = t1 * N1_ + s1;
#pragma unroll 4
    for (int h = 0; h < H_; ++h) {
        float acc = sb2[h];
#pragma unroll
        for (int k = 0; k < H_; ++k) acc = fmaf(hk[k], sW2[h * H_ + k], acc);
        if (type_ptr) acc += type_ptr[h];
        if (loc_ptr)  acc += loc_ptr[h];
        float* p = outb + (size_t)h * PLANE_;
        unsafeAtomicAdd(p + off1, acc);
        unsafeAtomicAdd(p + off2, acc);
    }
}

// ============================================================================
extern "C" void kernel_launch(void* const* d_in, const int* in_sizes, int n_in,
                              void* d_out, int out_size, void* d_ws, size_t ws_size,
                              hipStream_t stream)
{
    const float4* edge_feat      = (const float4*)d_in[0];
    const int*    edge_index     = (const int*)  d_in[2];
    const void*   edge_mask      =               d_in[3];
    const int*    nlig           = (const int*)  d_in[4];
    const float*  structural_w   = (const float*)d_in[5];
    const float*  plip_protein_w = (const float*)d_in[6];
    const float*  plip_ligand_w  = (const float*)d_in[7];
    const float*  plip_inter_w   = (const float*)d_in[8];
    const float*  loc_w          = (const float*)d_in[9];
    const float*  virtual_w      = (const float*)d_in[10];
    const float*  W1             = (const float*)d_in[11];
    const float*  b1             = (const float*)d_in[12];
    const float*  W2             = (const float*)d_in[13];
    const float*  b2             = (const float*)d_in[14];
    float* out = (float*)d_out;

    if (ws_size >= WS_NEED) {
        char* ws = (char*)d_ws;
        int*   counts = (int*)  (ws + WS_COUNTS);
        float* T      = (float*)(ws + WS_T);
        float* A      = (float*)(ws + WS_A);
        float* Bv     = (float*)(ws + WS_B);
        int2*  bins2  = (int2*) (ws + WS_BINS2);

        prep_kernel<<<25, 256, 0, stream>>>(W1, b1, W2, b2, T, A, Bv, counts);
        bin_kernel<<<(B_ * E_) / 256, 256, 0, stream>>>(
            edge_feat, edge_index, edge_mask, nlig, T, counts, bins2);
        chunk_kernel<<<GBLK_, 512, 0, stream>>>(
            structural_w, plip_protein_w, plip_ligand_w, plip_inter_w,
            loc_w, virtual_w, A, Bv, counts, bins2, out);
    } else {
        unsigned int nth  = (unsigned int)(TOTAL_ / 4);
        unsigned int nblk = (nth + 255u) / 256u;
        init_out_kernel<<<nblk, 256, 0, stream>>>(out, virtual_w);
        edge_kernel<<<(B_ * E_) / 256, 256, 0, stream>>>(
            edge_feat, edge_index, edge_mask, nlig,
            structural_w, plip_protein_w, plip_ligand_w, plip_inter_w,
            loc_w, W1, b1, W2, b2, out);
    }
}